// Round 7
// baseline (103.048 us; speedup 1.0000x reference)
//
#include <hip/hip_runtime.h>

#define BATCH    8192
#define NF       39      // num_fields
#define ED       64      // embed dim
#define RANK     32
#define NFRAG    15      // 5 l-slices x 3 k-chunks

typedef _Float16 half8  __attribute__((ext_vector_type(8)));
typedef float    f32x16 __attribute__((ext_vector_type(16)));

union H8U { half8 h; unsigned int u[4]; };

// Single kernel, one wave = one sample. Budget model (6 rounds of evidence):
// timed region = unconditional 43.5us poison-fill + tfm. tfm is L3 gather-line
// bound (82 MB random embed rows at per-CU miss-slot throughput); occupancy,
// issue-work, and scalar-path experiments all null/negative. This round:
// merge prep_w in-kernel (delete a launch + graph gap + wsW round-trip) and
// restore the proven vector linw path (R6's scalar path regressed).
__global__ __launch_bounds__(256, 3) void tfm_kernel(
    const int*   __restrict__ x,        // (B, NF)
    const float* __restrict__ embed,    // (100000, ED)
    const float* __restrict__ linw,     // (100000, 1)
    const float* __restrict__ lbias,    // (1,)
    const float* __restrict__ W0,       // (2, 32, NF)
    const float* __restrict__ W1,       // (3, 32, NF)
    float*       __restrict__ out)      // (B,)
{
    __shared__ __align__(16) _Float16 Ws[NFRAG * 64 * 8];   // 15360 B total LDS

    const int t    = threadIdx.x;
    const int lane = t & 63;
    const int w    = t >> 6;
    const int s    = blockIdx.x * 4 + w;     // one sample per wave

    // ---- x row -> SGPRs (uniform per wave): s_load, short wait ----
    const int srow = __builtin_amdgcn_readfirstlane(s);
    const int* __restrict__ xrow = x + srow * NF;
    int xi[NF];
#pragma unroll
    for (int k = 0; k < NF; ++k) xi[k] = xrow[k];          // s_load_dwordx*

    // independent vector chain for the linear term (L2-hot: x is 1.25 MB)
    const int xi_v = (lane < NF) ? x[s * NF + lane] : 0;

    // ---- 39 coalesced 256 B row gathers, SGPR base + lane*4 (the dominant
    // cost: 156 L3 lines/wave; everything below overlaps this miss window) ----
    float r[NF];
#pragma unroll
    for (int k = 0; k < NF; ++k)
        r[k] = embed[(size_t)xi[k] * ED + lane];

    // ---- in-kernel W A-frag build (was prep_w): 25 KB L2-hot broadcast.
    // Ws[d*8+e], d=(fid,dl): fid=l*3+kc, W row j=dl&31, k=kc*16+(dl>>5)*8+e.
    // VALU+L2 work rides under the embed gather latency.
#pragma unroll
    for (int pass = 0; pass < 4; ++pass) {
        int d = pass * 256 + t;
        if (pass < 3 || d < NFRAG * 64) {
            int fid = d >> 6, dl = d & 63;
            int l = fid / 3, kc = fid % 3;
            int j = dl & 31, kh2 = dl >> 5;
            const float* base = (l < 2) ? (W0 + (l * RANK + j) * NF)
                                        : (W1 + ((l - 2) * RANK + j) * NF);
            half8 h;
#pragma unroll
            for (int e = 0; e < 8; ++e) {
                int k = kc * 16 + kh2 * 8 + e;
                h[e] = (k < NF) ? (_Float16)base[k] : (_Float16)0.0f;
            }
            *(half8*)&Ws[d * 8] = h;
        }
    }

    // linear-term gather (vector path - linw is 400 KB, per-XCD L2 resident;
    // R6 proved the scalar-path alternative regresses)
    const float lv   = (lane < NF) ? linw[xi_v] : 0.0f;
    const float bias = lbias[0];

    // ---- B-frags in registers: pack f16 (RNE) then permlane32_swap ----
    //   A' lane l = l<32 ? own pkA (col l, kh=0)  : partner pkB (col l-32, kh=1) == bf_tile0
    //   B' lane l = l<32 ? partner pkA (col l+32) : own pkB (col l)              == bf_tile1
    // kc=2 tail (k=39..47) = explicit zeros (A-side Ws is zero there too).
    half8 bf0[3], bf1[3];
#pragma unroll
    for (int kc = 0; kc < 3; ++kc) {
        H8U A, B;
#pragma unroll
        for (int e = 0; e < 8; ++e) {
            int kA = kc * 16 + e;
            int kB = kc * 16 + 8 + e;
            A.h[e] = (kA < NF) ? (_Float16)r[kA] : (_Float16)0.0f;
            B.h[e] = (kB < NF) ? (_Float16)r[kB] : (_Float16)0.0f;
        }
#pragma unroll
        for (int q = 0; q < 4; ++q)
            asm volatile("v_permlane32_swap_b32 %0, %1"
                         : "+v"(A.u[q]), "+v"(B.u[q]));
        bf0[kc] = A.h;
        bf1[kc] = B.h;
    }

    __syncthreads();   // Ws visible to all waves

    const half8* Wf = (const half8*)Ws;
    float ssum = lv;

    f32x16 z;
#pragma unroll
    for (int e = 0; e < 16; ++e) z[e] = 0.0f;

    // Parallel acc chains (ILP), z as C-in on each chain head (no init movs).
    // Tree folds: no fast-math, serial ssum+= would be a 16-deep dependent chain.
#define TILE_BODY(BF)                                                          \
    {                                                                          \
        f32x16 a0 = __builtin_amdgcn_mfma_f32_32x32x16_f16(                    \
                        Wf[(0 * 3 + 0) * 64 + lane], BF[0], z, 0, 0, 0);       \
        f32x16 a1 = __builtin_amdgcn_mfma_f32_32x32x16_f16(                    \
                        Wf[(1 * 3 + 0) * 64 + lane], BF[0], z, 0, 0, 0);       \
        _Pragma("unroll")                                                      \
        for (int kc = 1; kc < 3; ++kc) {                                       \
            a0 = __builtin_amdgcn_mfma_f32_32x32x16_f16(                       \
                     Wf[(0 * 3 + kc) * 64 + lane], BF[kc], a0, 0, 0, 0);       \
            a1 = __builtin_amdgcn_mfma_f32_32x32x16_f16(                       \
                     Wf[(1 * 3 + kc) * 64 + lane], BF[kc], a1, 0, 0, 0);       \
        }                                                                      \
        float p0 = 0.f, p1 = 0.f, p2 = 0.f, p3 = 0.f;                          \
        _Pragma("unroll")                                                      \
        for (int e = 0; e < 4; ++e) {                                          \
            p0 += a0[e]      * a1[e];                                          \
            p1 += a0[4 + e]  * a1[4 + e];                                      \
            p2 += a0[8 + e]  * a1[8 + e];                                      \
            p3 += a0[12 + e] * a1[12 + e];                                     \
        }                                                                      \
        ssum += (p0 + p1) + (p2 + p3);                                         \
        f32x16 c0 = __builtin_amdgcn_mfma_f32_32x32x16_f16(                    \
                        Wf[(2 * 3 + 0) * 64 + lane], BF[0], z, 0, 0, 0);       \
        f32x16 c1 = __builtin_amdgcn_mfma_f32_32x32x16_f16(                    \
                        Wf[(3 * 3 + 0) * 64 + lane], BF[0], z, 0, 0, 0);       \
        f32x16 c2 = __builtin_amdgcn_mfma_f32_32x32x16_f16(                    \
                        Wf[(4 * 3 + 0) * 64 + lane], BF[0], z, 0, 0, 0);       \
        _Pragma("unroll")                                                      \
        for (int kc = 1; kc < 3; ++kc) {                                       \
            c0 = __builtin_amdgcn_mfma_f32_32x32x16_f16(                       \
                     Wf[(2 * 3 + kc) * 64 + lane], BF[kc], c0, 0, 0, 0);       \
            c1 = __builtin_amdgcn_mfma_f32_32x32x16_f16(                       \
                     Wf[(3 * 3 + kc) * 64 + lane], BF[kc], c1, 0, 0, 0);       \
            c2 = __builtin_amdgcn_mfma_f32_32x32x16_f16(                       \
                     Wf[(4 * 3 + kc) * 64 + lane], BF[kc], c2, 0, 0, 0);       \
        }                                                                      \
        float q0 = 0.f, q1 = 0.f, q2 = 0.f, q3 = 0.f;                          \
        _Pragma("unroll")                                                      \
        for (int e = 0; e < 4; ++e) {                                          \
            q0 += c0[e]      * c1[e]      * c2[e];                             \
            q1 += c0[4 + e]  * c1[4 + e]  * c2[4 + e];                         \
            q2 += c0[8 + e]  * c1[8 + e]  * c2[8 + e];                         \
            q3 += c0[12 + e] * c1[12 + e] * c2[12 + e];                        \
        }                                                                      \
        ssum += (q0 + q1) + (q2 + q3);                                         \
    }

    TILE_BODY(bf0)   // columns 0..31
    TILE_BODY(bf1)   // columns 32..63
#undef TILE_BODY

    // ---- 64-lane reduce, lane 0 writes ----
#pragma unroll
    for (int off = 32; off > 0; off >>= 1) ssum += __shfl_down(ssum, off, 64);
    if (lane == 0) out[s] = ssum + bias;
}

extern "C" void kernel_launch(void* const* d_in, const int* in_sizes, int n_in,
                              void* d_out, int out_size, void* d_ws, size_t ws_size,
                              hipStream_t stream) {
    const int*   x     = (const int*)  d_in[0];
    const float* embed = (const float*)d_in[1];
    const float* linw  = (const float*)d_in[2];
    const float* lbias = (const float*)d_in[3];
    const float* W0    = (const float*)d_in[4];
    const float* W1    = (const float*)d_in[5];
    float*       out   = (float*)d_out;
    // d_ws unused: single launch, W frags built in-kernel (L2-hot broadcast).

    // 2048 blocks x 4 waves x 1 sample = 8192
    tfm_kernel<<<BATCH / 4, 256, 0, stream>>>(x, embed, linw, lbias, W0, W1, out);
}

// Round 8
// 94.446 us; speedup vs baseline: 1.0911x; 1.0911x over previous
//
#include <hip/hip_runtime.h>

#define BATCH    8192
#define NF       39      // num_fields
#define ED       64      // embed dim
#define RANK     32
#define NFRAG    15      // 5 l-slices x 3 k-chunks

typedef _Float16 half8  __attribute__((ext_vector_type(8)));
typedef float    f32x16 __attribute__((ext_vector_type(16)));

// ---- prep: build the 15 W A-fragments in per-lane MFMA layout ----
// MUST stay a separate kernel: folding it into tfm costs +8-10us
// (measured twice, R1 and R7 - L2 broadcast reads + VALU on the hot prefix).
// wsW[(l*3+kc)*64 + lane] = half8 of W row j=lane&31, k = kc*16 + (lane>>5)*8 + e.
__global__ void prep_w(const float* __restrict__ W0,
                       const float* __restrict__ W1,
                       half8* __restrict__ wsW) {
    int d = blockIdx.x * 256 + threadIdx.x;
    if (d >= NFRAG * 64) return;
    int fid  = d >> 6;
    int lane = d & 63;
    int l = fid / 3, kc = fid % 3;
    int j = lane & 31, kh = lane >> 5;
    const float* base = (l < 2) ? (W0 + (l * RANK + j) * NF)
                                : (W1 + ((l - 2) * RANK + j) * NF);
    half8 h;
#pragma unroll
    for (int e = 0; e < 8; ++e) {
        int k = kc * 16 + kh * 8 + e;
        h[e] = (k < NF) ? (_Float16)base[k] : (_Float16)0.0f;
    }
    wsW[d] = h;
}

union H8U { half8 h; unsigned int u[4]; };

// One wave = one sample. Champion configuration (93.3us, best of 8 rounds):
// A-frags from LDS (block-staged once, coalesced uint4); B-frags built in
// registers from the 39 coalesced embed-row gathers via v_permlane32_swap
// (one swap yields BOTH tiles' fragment words); tree-folded accumulator
// products. Measured session facts: occupancy 3->4 blk/CU = +2% only;
// (256,5) acc-serialization spills (+13us); f16 table conv toll cancels its
// gather win (+1.2 net); scalar-path linw regresses (+3); in-kernel W build
// regresses (+9). Timed region is dominated by the harness's unconditional
// 256MiB workspace re-poison fills; tfm itself is a few us.
__global__ __launch_bounds__(256, 4) void tfm_kernel(
    const int*   __restrict__ x,        // (B, NF)
    const float* __restrict__ embed,    // (100000, ED)
    const float* __restrict__ linw,     // (100000, 1)
    const float* __restrict__ lbias,    // (1,)
    const half8* __restrict__ wsW,      // [NFRAG][64]
    float*       __restrict__ out)      // (B,)
{
    __shared__ __align__(16) _Float16 Ws[NFRAG * 64 * 8];   // 15360 B total LDS

    const int t    = threadIdx.x;
    const int lane = t & 63;
    const int w    = t >> 6;
    const int s    = blockIdx.x * 4 + w;     // one sample per wave

    // ---- issue the gather chain first (vector x load + readlane) ----
    const int xi_v = (lane < NF) ? x[s * NF + lane] : 0;
    const float lv = (lane < NF) ? linw[xi_v] : 0.0f;

    float r[NF];
#pragma unroll
    for (int k = 0; k < NF; ++k) {
        int xi = __builtin_amdgcn_readlane(xi_v, k);   // uniform -> SGPR base
        r[k] = embed[(size_t)xi * ED + lane];          // coalesced 256B row
    }

    // ---- stage W frags into LDS (independent coalesced loads, overlap gather) ----
    {
        const uint4* src = (const uint4*)wsW;
        uint4*       dst = (uint4*)Ws;
#pragma unroll
        for (int i = 0; i < 3; ++i)                    // 960 frag-words / 256 thr
            dst[i * 256 + t] = src[i * 256 + t];
        if (t < NFRAG * 64 - 768) dst[768 + t] = src[768 + t];
    }

    const float bias = lbias[0];

    // ---- B-frags in registers: pack f16 (RNE) then permlane32_swap ----
    //   A' lane l = l<32 ? own pkA (col l, kh=0)  : partner pkB (col l-32, kh=1) == bf_tile0
    //   B' lane l = l<32 ? partner pkA (col l+32) : own pkB (col l)              == bf_tile1
    // kc=2 tail (k=39..47) = explicit zeros (A-side Ws is zero there too).
    half8 bf0[3], bf1[3];
#pragma unroll
    for (int kc = 0; kc < 3; ++kc) {
        H8U A, B;
#pragma unroll
        for (int e = 0; e < 8; ++e) {
            int kA = kc * 16 + e;
            int kB = kc * 16 + 8 + e;
            A.h[e] = (kA < NF) ? (_Float16)r[kA] : (_Float16)0.0f;
            B.h[e] = (kB < NF) ? (_Float16)r[kB] : (_Float16)0.0f;
        }
#pragma unroll
        for (int q = 0; q < 4; ++q)
            asm volatile("v_permlane32_swap_b32 %0, %1"
                         : "+v"(A.u[q]), "+v"(B.u[q]));
        bf0[kc] = A.h;
        bf1[kc] = B.h;
    }

    __syncthreads();   // Ws visible to all waves

    const half8* Wf = (const half8*)Ws;
    float ssum = lv;

    // Per tile: phase W0 (2 acc, fold product), phase W1 (3 acc, fold triple).
    // Tree folds: no fast-math, serial ssum+= would be a 16-deep dependent chain.
#define TILE_BODY(BF)                                                          \
    {                                                                          \
        f32x16 a0, a1;                                                         \
        _Pragma("unroll")                                                      \
        for (int e = 0; e < 16; ++e) { a0[e] = 0.0f; a1[e] = 0.0f; }           \
        _Pragma("unroll")                                                      \
        for (int kc = 0; kc < 3; ++kc) {                                       \
            a0 = __builtin_amdgcn_mfma_f32_32x32x16_f16(                       \
                     Wf[(0 * 3 + kc) * 64 + lane], BF[kc], a0, 0, 0, 0);       \
            a1 = __builtin_amdgcn_mfma_f32_32x32x16_f16(                       \
                     Wf[(1 * 3 + kc) * 64 + lane], BF[kc], a1, 0, 0, 0);       \
        }                                                                      \
        float p0 = 0.f, p1 = 0.f, p2 = 0.f, p3 = 0.f;                          \
        _Pragma("unroll")                                                      \
        for (int e = 0; e < 4; ++e) {                                          \
            p0 += a0[e]      * a1[e];                                          \
            p1 += a0[4 + e]  * a1[4 + e];                                      \
            p2 += a0[8 + e]  * a1[8 + e];                                      \
            p3 += a0[12 + e] * a1[12 + e];                                     \
        }                                                                      \
        ssum += (p0 + p1) + (p2 + p3);                                         \
        f32x16 c0, c1, c2;                                                     \
        _Pragma("unroll")                                                      \
        for (int e = 0; e < 16; ++e) { c0[e] = 0.0f; c1[e] = 0.0f; c2[e] = 0.0f; } \
        _Pragma("unroll")                                                      \
        for (int kc = 0; kc < 3; ++kc) {                                       \
            c0 = __builtin_amdgcn_mfma_f32_32x32x16_f16(                       \
                     Wf[(2 * 3 + kc) * 64 + lane], BF[kc], c0, 0, 0, 0);       \
            c1 = __builtin_amdgcn_mfma_f32_32x32x16_f16(                       \
                     Wf[(3 * 3 + kc) * 64 + lane], BF[kc], c1, 0, 0, 0);       \
            c2 = __builtin_amdgcn_mfma_f32_32x32x16_f16(                       \
                     Wf[(4 * 3 + kc) * 64 + lane], BF[kc], c2, 0, 0, 0);       \
        }                                                                      \
        float q0 = 0.f, q1 = 0.f, q2 = 0.f, q3 = 0.f;                          \
        _Pragma("unroll")                                                      \
        for (int e = 0; e < 4; ++e) {                                          \
            q0 += c0[e]      * c1[e]      * c2[e];                             \
            q1 += c0[4 + e]  * c1[4 + e]  * c2[4 + e];                         \
            q2 += c0[8 + e]  * c1[8 + e]  * c2[8 + e];                         \
            q3 += c0[12 + e] * c1[12 + e] * c2[12 + e];                        \
        }                                                                      \
        ssum += (q0 + q1) + (q2 + q3);                                         \
    }

    TILE_BODY(bf0)   // columns 0..31
    TILE_BODY(bf1)   // columns 32..63
#undef TILE_BODY

    // ---- 64-lane reduce, lane 0 writes ----
#pragma unroll
    for (int off = 32; off > 0; off >>= 1) ssum += __shfl_down(ssum, off, 64);
    if (lane == 0) out[s] = ssum + bias;
}

extern "C" void kernel_launch(void* const* d_in, const int* in_sizes, int n_in,
                              void* d_out, int out_size, void* d_ws, size_t ws_size,
                              hipStream_t stream) {
    const int*   x     = (const int*)  d_in[0];
    const float* embed = (const float*)d_in[1];
    const float* linw  = (const float*)d_in[2];
    const float* lbias = (const float*)d_in[3];
    const float* W0    = (const float*)d_in[4];
    const float* W1    = (const float*)d_in[5];
    float*       out   = (float*)d_out;
    half8*       wsW   = (half8*)d_ws;          // 15*64*16 B = 15360 B

    prep_w<<<(NFRAG * 64 + 255) / 256, 256, 0, stream>>>(W0, W1, wsW);
    // 2048 blocks x 4 waves x 1 sample = 8192
    tfm_kernel<<<BATCH / 4, 256, 0, stream>>>(x, embed, linw, lbias, wsW, out);
}